// Round 1
// baseline (1290.437 us; speedup 1.0000x reference)
//
#include <hip/hip_runtime.h>

#define OUTC 512
#define INC 512

// ---------- degree / norm ----------
__global__ void k_deg_init(float* __restrict__ deg, int N) {
    int i = blockIdx.x * blockDim.x + threadIdx.x;
    if (i < N) deg[i] = 1.0f;  // self-loop
}

__global__ void k_deg_count(const int* __restrict__ dst, float* __restrict__ deg, int E) {
    int e = blockIdx.x * blockDim.x + threadIdx.x;
    if (e < E) atomicAdd(&deg[dst[e]], 1.0f);
}

__global__ void k_dinv(float* __restrict__ deg, int N) {
    int i = blockIdx.x * blockDim.x + threadIdx.x;
    if (i < N) deg[i] = rsqrtf(deg[i]);
}

// ---------- time embedding: temb[j] = sum_k t_emb[k]*Wt[k][j] + bt[j] ----------
__global__ void k_temb(const float* __restrict__ t_emb, const float* __restrict__ Wt,
                       const float* __restrict__ bt, float* __restrict__ temb, int TC) {
    int j = threadIdx.x;  // 512 threads, 1 block
    float s = bt[j];
    for (int k = 0; k < TC; ++k) s += t_emb[k] * Wt[k * OUTC + j];
    temb[j] = s;
}

// ---------- fp32 GEMM: XW[M,512] = X[M,512] @ W[512,512] ----------
// 64x64 tile, K-tile 16, 256 threads, 4x4 acc/thread
__global__ __launch_bounds__(256) void k_gemm(const float* __restrict__ X,
                                              const float* __restrict__ W,
                                              float* __restrict__ XW, int M) {
    __shared__ float As[16][64 + 1];  // [k][m], +1 pad
    __shared__ float Bs[16][64];      // [k][n]

    const int tid = threadIdx.x;
    const int m0 = blockIdx.x * 64;
    const int n0 = blockIdx.y * 64;
    const int tx = tid & 15;   // 0..15 -> 4 cols each
    const int ty = tid >> 4;   // 0..15 -> 4 rows each

    float acc[4][4] = {};

    for (int k0 = 0; k0 < INC; k0 += 16) {
        // load A tile: 64 rows x 16 cols = 256 float4s
        {
            int row = tid >> 2, c4 = tid & 3;
            int gm = m0 + row;
            float4 v = make_float4(0.f, 0.f, 0.f, 0.f);
            if (gm < M) v = *(const float4*)(X + (size_t)gm * INC + k0 + c4 * 4);
            As[c4 * 4 + 0][row] = v.x;
            As[c4 * 4 + 1][row] = v.y;
            As[c4 * 4 + 2][row] = v.z;
            As[c4 * 4 + 3][row] = v.w;
        }
        // load B tile: 16 rows x 64 cols = 256 float4s
        {
            int row = tid >> 4, c4 = tid & 15;
            float4 v = *(const float4*)(W + (size_t)(k0 + row) * OUTC + n0 + c4 * 4);
            *(float4*)(&Bs[row][c4 * 4]) = v;
        }
        __syncthreads();

#pragma unroll
        for (int kk = 0; kk < 16; ++kk) {
            float a0 = As[kk][ty * 4 + 0];
            float a1 = As[kk][ty * 4 + 1];
            float a2 = As[kk][ty * 4 + 2];
            float a3 = As[kk][ty * 4 + 3];
            float4 bv = *(const float4*)(&Bs[kk][tx * 4]);
            acc[0][0] += a0 * bv.x; acc[0][1] += a0 * bv.y; acc[0][2] += a0 * bv.z; acc[0][3] += a0 * bv.w;
            acc[1][0] += a1 * bv.x; acc[1][1] += a1 * bv.y; acc[1][2] += a1 * bv.z; acc[1][3] += a1 * bv.w;
            acc[2][0] += a2 * bv.x; acc[2][1] += a2 * bv.y; acc[2][2] += a2 * bv.z; acc[2][3] += a2 * bv.w;
            acc[3][0] += a3 * bv.x; acc[3][1] += a3 * bv.y; acc[3][2] += a3 * bv.z; acc[3][3] += a3 * bv.w;
        }
        __syncthreads();
    }

#pragma unroll
    for (int i = 0; i < 4; ++i) {
        int gm = m0 + ty * 4 + i;
        if (gm < M) {
            float4 o = make_float4(acc[i][0], acc[i][1], acc[i][2], acc[i][3]);
            *(float4*)(XW + (size_t)gm * OUTC + n0 + tx * 4) = o;
        }
    }
}

// ---------- self-loop + bias + time (plain store: handles poisoned d_out) ----------
__global__ void k_self(const float* __restrict__ XW, const float* __restrict__ dinv,
                       const float* __restrict__ b, const float* __restrict__ temb,
                       float* __restrict__ out, int N) {
    int idx = blockIdx.x * blockDim.x + threadIdx.x;  // over N*128 float4s
    if (idx >= N * 128) return;
    int i = idx >> 7;
    int c = (idx & 127) * 4;
    float di = dinv[i];
    float nrm = di * di;
    float4 xv = *(const float4*)(XW + (size_t)i * OUTC + c);
    float4 bv = *(const float4*)(b + c);
    float4 tv = *(const float4*)(temb + c);
    float4 o;
    o.x = nrm * xv.x + bv.x + tv.x;
    o.y = nrm * xv.y + bv.y + tv.y;
    o.z = nrm * xv.z + bv.z + tv.z;
    o.w = nrm * xv.w + bv.w + tv.w;
    *(float4*)(out + (size_t)i * OUTC + c) = o;
}

// ---------- edge scatter: out[dst] += dinv[src]*dinv[dst] * xw[src] ----------
__global__ __launch_bounds__(128) void k_edge(const int* __restrict__ src,
                                              const int* __restrict__ dst,
                                              const float* __restrict__ XW,
                                              const float* __restrict__ dinv,
                                              float* __restrict__ out, int E) {
    int e = blockIdx.x;
    if (e >= E) return;
    int s = src[e], d = dst[e];
    float nrm = dinv[s] * dinv[d];
    int c = threadIdx.x * 4;
    float4 v = *(const float4*)(XW + (size_t)s * OUTC + c);
    float* o = out + (size_t)d * OUTC + c;
    atomicAdd(o + 0, nrm * v.x);
    atomicAdd(o + 1, nrm * v.y);
    atomicAdd(o + 2, nrm * v.z);
    atomicAdd(o + 3, nrm * v.w);
}

extern "C" void kernel_launch(void* const* d_in, const int* in_sizes, int n_in,
                              void* d_out, int out_size, void* d_ws, size_t ws_size,
                              hipStream_t stream) {
    const float* x     = (const float*)d_in[0];
    const float* t_emb = (const float*)d_in[1];
    const int*   ei    = (const int*)d_in[2];
    const float* W     = (const float*)d_in[3];
    const float* b     = (const float*)d_in[4];
    const float* Wt    = (const float*)d_in[5];
    const float* bt    = (const float*)d_in[6];
    float* out = (float*)d_out;

    const int N  = in_sizes[0] / INC;   // 10000
    const int E  = in_sizes[2] / 2;     // 160000
    const int TC = in_sizes[1];         // 256

    char* ws = (char*)d_ws;
    float* xw   = (float*)ws;                                   // N*512 floats
    size_t off  = (size_t)N * OUTC * sizeof(float);
    float* dinv = (float*)(ws + off);                           // N floats (deg then dinv)
    off += ((size_t)N * sizeof(float) + 255) & ~(size_t)255;
    float* temb = (float*)(ws + off);                           // 512 floats

    const int* srcIdx = ei;
    const int* dstIdx = ei + E;

    k_deg_init<<<(N + 255) / 256, 256, 0, stream>>>(dinv, N);
    k_deg_count<<<(E + 255) / 256, 256, 0, stream>>>(dstIdx, dinv, E);
    k_dinv<<<(N + 255) / 256, 256, 0, stream>>>(dinv, N);
    k_temb<<<1, OUTC, 0, stream>>>(t_emb, Wt, bt, temb, TC);

    dim3 gemm_grid((N + 63) / 64, OUTC / 64);
    k_gemm<<<gemm_grid, 256, 0, stream>>>(x, W, xw, N);

    k_self<<<(N * 128 + 255) / 256, 256, 0, stream>>>(xw, dinv, b, temb, out, N);
    k_edge<<<E, 128, 0, stream>>>(srcIdx, dstIdx, xw, dinv, out, E);
}

// Round 2
// 297.470 us; speedup vs baseline: 4.3380x; 4.3380x over previous
//
#include <hip/hip_runtime.h>

#define OUTC 512
#define INC 512
#define SCAN_T 1024

// ---------- init counts ----------
__global__ void k_zero(int* __restrict__ counts, int N) {
    int i = blockIdx.x * blockDim.x + threadIdx.x;
    if (i < N) counts[i] = 0;
}

// ---------- dst histogram (in-degree, no self-loop) ----------
__global__ void k_count(const int* __restrict__ dst, int* __restrict__ counts, int E) {
    int e = blockIdx.x * blockDim.x + threadIdx.x;
    if (e < E) atomicAdd(&counts[dst[e]], 1);
}

// ---------- dinv = rsqrt(indeg + 1) ----------
__global__ void k_dinv(const int* __restrict__ counts, float* __restrict__ dinv, int N) {
    int i = blockIdx.x * blockDim.x + threadIdx.x;
    if (i < N) dinv[i] = rsqrtf((float)counts[i] + 1.0f);
}

// ---------- single-block exclusive scan -> row_start[N+1], cursor ----------
__global__ __launch_bounds__(SCAN_T) void k_scan(const int* __restrict__ counts,
                                                 int* __restrict__ row_start,
                                                 int* __restrict__ cursor, int N) {
    __shared__ int sums[SCAN_T];
    int t = threadIdx.x;
    int C = (N + SCAN_T - 1) / SCAN_T;
    int lo = t * C;
    int hi = lo + C; if (hi > N) hi = N; if (lo > N) lo = N;
    int s = 0;
    for (int i = lo; i < hi; ++i) s += counts[i];
    sums[t] = s;
    __syncthreads();
    // Hillis-Steele inclusive scan
    for (int off = 1; off < SCAN_T; off <<= 1) {
        int v = (t >= off) ? sums[t - off] : 0;
        __syncthreads();
        sums[t] += v;
        __syncthreads();
    }
    int run = (t == 0) ? 0 : sums[t - 1];
    for (int i = lo; i < hi; ++i) {
        row_start[i] = run;
        cursor[i] = run;
        run += counts[i];
    }
    if (hi == N) row_start[N] = run;  // run == total for all threads past the end
}

// ---------- scatter edge src ids into CSR slots ----------
__global__ void k_scatter(const int* __restrict__ src, const int* __restrict__ dst,
                          int* __restrict__ cursor, int* __restrict__ esrc, int E) {
    int e = blockIdx.x * blockDim.x + threadIdx.x;
    if (e < E) {
        int d = dst[e];
        int pos = atomicAdd(&cursor[d], 1);
        esrc[pos] = src[e];
    }
}

// ---------- time embedding ----------
__global__ void k_temb(const float* __restrict__ t_emb, const float* __restrict__ Wt,
                       const float* __restrict__ bt, float* __restrict__ temb, int TC) {
    int j = threadIdx.x;  // 512 threads, 1 block
    float s = bt[j];
    for (int k = 0; k < TC; ++k) s += t_emb[k] * Wt[k * OUTC + j];
    temb[j] = s;
}

// ---------- fp32 GEMM: XW[M,512] = X[M,512] @ W[512,512] ----------
__global__ __launch_bounds__(256) void k_gemm(const float* __restrict__ X,
                                              const float* __restrict__ W,
                                              float* __restrict__ XW, int M) {
    __shared__ float As[16][64 + 1];
    __shared__ float Bs[16][64];

    const int tid = threadIdx.x;
    const int m0 = blockIdx.x * 64;
    const int n0 = blockIdx.y * 64;
    const int tx = tid & 15;
    const int ty = tid >> 4;

    float acc[4][4] = {};

    for (int k0 = 0; k0 < INC; k0 += 16) {
        {
            int row = tid >> 2, c4 = tid & 3;
            int gm = m0 + row;
            float4 v = make_float4(0.f, 0.f, 0.f, 0.f);
            if (gm < M) v = *(const float4*)(X + (size_t)gm * INC + k0 + c4 * 4);
            As[c4 * 4 + 0][row] = v.x;
            As[c4 * 4 + 1][row] = v.y;
            As[c4 * 4 + 2][row] = v.z;
            As[c4 * 4 + 3][row] = v.w;
        }
        {
            int row = tid >> 4, c4 = tid & 15;
            float4 v = *(const float4*)(W + (size_t)(k0 + row) * OUTC + n0 + c4 * 4);
            *(float4*)(&Bs[row][c4 * 4]) = v;
        }
        __syncthreads();

#pragma unroll
        for (int kk = 0; kk < 16; ++kk) {
            float a0 = As[kk][ty * 4 + 0];
            float a1 = As[kk][ty * 4 + 1];
            float a2 = As[kk][ty * 4 + 2];
            float a3 = As[kk][ty * 4 + 3];
            float4 bv = *(const float4*)(&Bs[kk][tx * 4]);
            acc[0][0] += a0 * bv.x; acc[0][1] += a0 * bv.y; acc[0][2] += a0 * bv.z; acc[0][3] += a0 * bv.w;
            acc[1][0] += a1 * bv.x; acc[1][1] += a1 * bv.y; acc[1][2] += a1 * bv.z; acc[1][3] += a1 * bv.w;
            acc[2][0] += a2 * bv.x; acc[2][1] += a2 * bv.y; acc[2][2] += a2 * bv.z; acc[2][3] += a2 * bv.w;
            acc[3][0] += a3 * bv.x; acc[3][1] += a3 * bv.y; acc[3][2] += a3 * bv.z; acc[3][3] += a3 * bv.w;
        }
        __syncthreads();
    }

#pragma unroll
    for (int i = 0; i < 4; ++i) {
        int gm = m0 + ty * 4 + i;
        if (gm < M) {
            float4 o = make_float4(acc[i][0], acc[i][1], acc[i][2], acc[i][3]);
            *(float4*)(XW + (size_t)gm * OUTC + n0 + tx * 4) = o;
        }
    }
}

// ---------- CSR gather: out[d] = sum_{s in N(d)} dinv[s]*dinv[d]*xw[s]
//            + dinv[d]^2*xw[d] + b + temb  (plain stores, no atomics) ----------
__global__ __launch_bounds__(128) void k_gather(const int* __restrict__ esrc,
                                                const int* __restrict__ row_start,
                                                const float* __restrict__ XW,
                                                const float* __restrict__ dinv,
                                                const float* __restrict__ b,
                                                const float* __restrict__ temb,
                                                float* __restrict__ out, int N) {
    int d = blockIdx.x;
    if (d >= N) return;
    int c = threadIdx.x * 4;
    int s0 = row_start[d];
    int s1 = row_start[d + 1];
    float di = dinv[d];

    float4 xv = *(const float4*)(XW + (size_t)d * OUTC + c);
    float4 bv = *(const float4*)(b + c);
    float4 tv = *(const float4*)(temb + c);
    float nd = di * di;
    float ax = nd * xv.x + bv.x + tv.x;
    float ay = nd * xv.y + bv.y + tv.y;
    float az = nd * xv.z + bv.z + tv.z;
    float aw = nd * xv.w + bv.w + tv.w;

    for (int i = s0; i < s1; ++i) {
        int s = esrc[i];
        float nrm = dinv[s] * di;
        float4 v = *(const float4*)(XW + (size_t)s * OUTC + c);
        ax += nrm * v.x;
        ay += nrm * v.y;
        az += nrm * v.z;
        aw += nrm * v.w;
    }

    float4 o = make_float4(ax, ay, az, aw);
    *(float4*)(out + (size_t)d * OUTC + c) = o;
}

extern "C" void kernel_launch(void* const* d_in, const int* in_sizes, int n_in,
                              void* d_out, int out_size, void* d_ws, size_t ws_size,
                              hipStream_t stream) {
    const float* x     = (const float*)d_in[0];
    const float* t_emb = (const float*)d_in[1];
    const int*   ei    = (const int*)d_in[2];
    const float* W     = (const float*)d_in[3];
    const float* b     = (const float*)d_in[4];
    const float* Wt    = (const float*)d_in[5];
    const float* bt    = (const float*)d_in[6];
    float* out = (float*)d_out;

    const int N  = in_sizes[0] / INC;   // 10000
    const int E  = in_sizes[2] / 2;     // 160000
    const int TC = in_sizes[1];         // 256

    char* ws = (char*)d_ws;
    size_t off = 0;
    float* xw = (float*)(ws + off);        off += (size_t)N * OUTC * sizeof(float);
    float* dinv = (float*)(ws + off);      off += ((size_t)N * sizeof(float) + 255) & ~(size_t)255;
    int* counts = (int*)(ws + off);        off += ((size_t)N * sizeof(int) + 255) & ~(size_t)255;
    int* row_start = (int*)(ws + off);     off += ((size_t)(N + 1) * sizeof(int) + 255) & ~(size_t)255;
    int* cursor = (int*)(ws + off);        off += ((size_t)N * sizeof(int) + 255) & ~(size_t)255;
    int* esrc = (int*)(ws + off);          off += ((size_t)E * sizeof(int) + 255) & ~(size_t)255;
    float* temb = (float*)(ws + off);      off += OUTC * sizeof(float);

    const int* srcIdx = ei;
    const int* dstIdx = ei + E;

    k_zero<<<(N + 255) / 256, 256, 0, stream>>>(counts, N);
    k_count<<<(E + 255) / 256, 256, 0, stream>>>(dstIdx, counts, E);
    k_dinv<<<(N + 255) / 256, 256, 0, stream>>>(counts, dinv, N);
    k_scan<<<1, SCAN_T, 0, stream>>>(counts, row_start, cursor, N);
    k_scatter<<<(E + 255) / 256, 256, 0, stream>>>(srcIdx, dstIdx, cursor, esrc, E);
    k_temb<<<1, OUTC, 0, stream>>>(t_emb, Wt, bt, temb, TC);

    dim3 gemm_grid((N + 63) / 64, OUTC / 64);
    k_gemm<<<gemm_grid, 256, 0, stream>>>(x, W, xw, N);

    k_gather<<<N, 128, 0, stream>>>(esrc, row_start, xw, dinv, b, temb, out, N);
}

// Round 3
// 184.095 us; speedup vs baseline: 7.0096x; 1.6159x over previous
//
#include <hip/hip_runtime.h>

#define OUTC 512
#define INC 512
#define SCAN_T 1024
#define LDA 40   // 32 + 8 bf16 pad -> 2-way bank aliasing only (free)

typedef __bf16 bf16x8 __attribute__((ext_vector_type(8)));
typedef float f32x4 __attribute__((ext_vector_type(4)));

static __device__ __forceinline__ unsigned short f2bf(float f) {
    unsigned u = __float_as_uint(f);
    unsigned r = u + 0x7fffu + ((u >> 16) & 1u);  // RNE
    return (unsigned short)(r >> 16);
}
static __device__ __forceinline__ float b2f(unsigned short h) {
    return __uint_as_float(((unsigned)h) << 16);
}

// ---------- CSR build ----------
__global__ void k_zero(int* __restrict__ counts, int N) {
    int i = blockIdx.x * blockDim.x + threadIdx.x;
    if (i < N) counts[i] = 0;
}

__global__ void k_count(const int* __restrict__ dst, int* __restrict__ counts, int E) {
    int e = blockIdx.x * blockDim.x + threadIdx.x;
    if (e < E) atomicAdd(&counts[dst[e]], 1);
}

__global__ void k_dinv(const int* __restrict__ counts, float* __restrict__ dinv, int N) {
    int i = blockIdx.x * blockDim.x + threadIdx.x;
    if (i < N) dinv[i] = rsqrtf((float)counts[i] + 1.0f);
}

__global__ __launch_bounds__(SCAN_T) void k_scan(const int* __restrict__ counts,
                                                 int* __restrict__ row_start,
                                                 int* __restrict__ cursor, int N) {
    __shared__ int sums[SCAN_T];
    int t = threadIdx.x;
    int C = (N + SCAN_T - 1) / SCAN_T;
    int lo = t * C;
    int hi = lo + C; if (hi > N) hi = N; if (lo > N) lo = N;
    int s = 0;
    for (int i = lo; i < hi; ++i) s += counts[i];
    sums[t] = s;
    __syncthreads();
    for (int off = 1; off < SCAN_T; off <<= 1) {
        int v = (t >= off) ? sums[t - off] : 0;
        __syncthreads();
        sums[t] += v;
        __syncthreads();
    }
    int run = (t == 0) ? 0 : sums[t - 1];
    for (int i = lo; i < hi; ++i) {
        row_start[i] = run;
        cursor[i] = run;
        run += counts[i];
    }
    if (hi == N) row_start[N] = run;
}

__global__ void k_scatter(const int* __restrict__ src, const int* __restrict__ dst,
                          int* __restrict__ cursor, int* __restrict__ esrc, int E) {
    int e = blockIdx.x * blockDim.x + threadIdx.x;
    if (e < E) {
        int d = dst[e];
        int pos = atomicAdd(&cursor[d], 1);
        esrc[pos] = src[e];
    }
}

// ---------- time embedding: one block per output column ----------
__global__ __launch_bounds__(256) void k_temb(const float* __restrict__ t_emb,
                                              const float* __restrict__ Wt,
                                              const float* __restrict__ bt,
                                              float* __restrict__ temb, int TC) {
    __shared__ float red[256];
    int j = blockIdx.x;
    int t = threadIdx.x;
    float p = 0.0f;
    for (int k = t; k < TC; k += 256) p += t_emb[k] * Wt[(size_t)k * OUTC + j];
    red[t] = p;
    __syncthreads();
    for (int s = 128; s > 0; s >>= 1) {
        if (t < s) red[t] += red[t + s];
        __syncthreads();
    }
    if (t == 0) temb[j] = red[0] + bt[j];
}

// ---------- W transpose (fp32): WT[n][k] = W[k][n] ----------
__global__ __launch_bounds__(256) void k_wt(const float* __restrict__ W, float* __restrict__ WT) {
    __shared__ float tile[32][33];
    int bk = blockIdx.x * 32, bn = blockIdx.y * 32;
    int tx = threadIdx.x & 31, ty = threadIdx.x >> 5;  // ty 0..7
    for (int r = ty; r < 32; r += 8)
        tile[r][tx] = W[(size_t)(bk + r) * OUTC + bn + tx];
    __syncthreads();
    for (int r = ty; r < 32; r += 8)
        WT[(size_t)(bn + r) * INC + bk + tx] = tile[tx][r];
}

// ---------- bf16 MFMA GEMM: XWB[M,512](bf16) = X[M,512] @ W[512,512]
//            128x128 tile, BK=32, 4 waves (2x2), inline fp32->bf16 staging ----------
__global__ __launch_bounds__(256) void k_gemm_mfma(const float* __restrict__ X,
                                                   const float* __restrict__ WT,
                                                   unsigned short* __restrict__ XWB, int M) {
    __shared__ unsigned short lds_a[128 * LDA];
    __shared__ unsigned short lds_b[128 * LDA];

    const int tid = threadIdx.x;
    const int lane = tid & 63;
    const int wave = tid >> 6;
    const int wm = (wave >> 1) * 64;
    const int wn = (wave & 1) * 64;
    const int m0 = blockIdx.x * 128;
    const int n0 = blockIdx.y * 128;

    const int l15 = lane & 15;
    const int k8 = (lane >> 4) * 8;

    f32x4 acc[4][4];
#pragma unroll
    for (int t = 0; t < 4; ++t)
#pragma unroll
        for (int u = 0; u < 4; ++u)
            acc[t][u] = (f32x4){0.f, 0.f, 0.f, 0.f};

    for (int k0 = 0; k0 < INC; k0 += 32) {
        // stage A: 128 rows x 32 k  (1024 float4s / 256 threads = 4 each)
#pragma unroll
        for (int i = 0; i < 4; ++i) {
            int f = tid + i * 256;
            int row = f >> 3, c4 = f & 7;
            int gm = m0 + row;
            float4 v = make_float4(0.f, 0.f, 0.f, 0.f);
            if (gm < M) v = *(const float4*)(X + (size_t)gm * INC + k0 + c4 * 4);
            ushort4 h = make_ushort4(f2bf(v.x), f2bf(v.y), f2bf(v.z), f2bf(v.w));
            *(ushort4*)(&lds_a[row * LDA + c4 * 4]) = h;
        }
        // stage B: 128 n-rows x 32 k from WT
#pragma unroll
        for (int i = 0; i < 4; ++i) {
            int f = tid + i * 256;
            int row = f >> 3, c4 = f & 7;
            float4 v = *(const float4*)(WT + (size_t)(n0 + row) * INC + k0 + c4 * 4);
            ushort4 h = make_ushort4(f2bf(v.x), f2bf(v.y), f2bf(v.z), f2bf(v.w));
            *(ushort4*)(&lds_b[row * LDA + c4 * 4]) = h;
        }
        __syncthreads();

        bf16x8 af[4];
#pragma unroll
        for (int t = 0; t < 4; ++t)
            af[t] = *(const bf16x8*)(&lds_a[(wm + t * 16 + l15) * LDA + k8]);
#pragma unroll
        for (int u = 0; u < 4; ++u) {
            bf16x8 bfr = *(const bf16x8*)(&lds_b[(wn + u * 16 + l15) * LDA + k8]);
#pragma unroll
            for (int t = 0; t < 4; ++t)
                acc[t][u] = __builtin_amdgcn_mfma_f32_16x16x32_bf16(af[t], bfr, acc[t][u], 0, 0, 0);
        }
        __syncthreads();
    }

    // epilogue: bf16 store
    const int rbase = (lane >> 4) * 4;
#pragma unroll
    for (int t = 0; t < 4; ++t) {
#pragma unroll
        for (int u = 0; u < 4; ++u) {
            int gcol = n0 + wn + u * 16 + l15;
#pragma unroll
            for (int r = 0; r < 4; ++r) {
                int grow = m0 + wm + t * 16 + rbase + r;
                if (grow < M)
                    XWB[(size_t)grow * OUTC + gcol] = f2bf(acc[t][u][r]);
            }
        }
    }
}

// ---------- CSR gather (bf16 xw): out = sum + self + bias + temb ----------
__global__ __launch_bounds__(128) void k_gather(const int* __restrict__ esrc,
                                                const int* __restrict__ row_start,
                                                const unsigned short* __restrict__ XWB,
                                                const float* __restrict__ dinv,
                                                const float* __restrict__ b,
                                                const float* __restrict__ temb,
                                                float* __restrict__ out, int N) {
    int d = blockIdx.x;
    if (d >= N) return;
    int c = threadIdx.x * 4;
    int s0 = row_start[d];
    int s1 = row_start[d + 1];
    float di = dinv[d];

    ushort4 xv = *(const ushort4*)(XWB + (size_t)d * OUTC + c);
    float4 bv = *(const float4*)(b + c);
    float4 tv = *(const float4*)(temb + c);
    float nd = di * di;
    float ax = nd * b2f(xv.x) + bv.x + tv.x;
    float ay = nd * b2f(xv.y) + bv.y + tv.y;
    float az = nd * b2f(xv.z) + bv.z + tv.z;
    float aw = nd * b2f(xv.w) + bv.w + tv.w;

    for (int i = s0; i < s1; ++i) {
        int s = esrc[i];
        float nrm = dinv[s] * di;
        ushort4 v = *(const ushort4*)(XWB + (size_t)s * OUTC + c);
        ax += nrm * b2f(v.x);
        ay += nrm * b2f(v.y);
        az += nrm * b2f(v.z);
        aw += nrm * b2f(v.w);
    }

    float4 o = make_float4(ax, ay, az, aw);
    *(float4*)(out + (size_t)d * OUTC + c) = o;
}

extern "C" void kernel_launch(void* const* d_in, const int* in_sizes, int n_in,
                              void* d_out, int out_size, void* d_ws, size_t ws_size,
                              hipStream_t stream) {
    const float* x     = (const float*)d_in[0];
    const float* t_emb = (const float*)d_in[1];
    const int*   ei    = (const int*)d_in[2];
    const float* W     = (const float*)d_in[3];
    const float* b     = (const float*)d_in[4];
    const float* Wt    = (const float*)d_in[5];
    const float* bt    = (const float*)d_in[6];
    float* out = (float*)d_out;

    const int N  = in_sizes[0] / INC;   // 10000
    const int E  = in_sizes[2] / 2;     // 160000
    const int TC = in_sizes[1];         // 256

    char* ws = (char*)d_ws;
    size_t off = 0;
    unsigned short* xwb = (unsigned short*)(ws + off);
    off += (((size_t)N + 128) * OUTC * sizeof(unsigned short) + 255) & ~(size_t)255;
    float* WT = (float*)(ws + off);        off += (size_t)INC * OUTC * sizeof(float);
    float* dinv = (float*)(ws + off);      off += ((size_t)N * sizeof(float) + 255) & ~(size_t)255;
    int* counts = (int*)(ws + off);        off += ((size_t)N * sizeof(int) + 255) & ~(size_t)255;
    int* row_start = (int*)(ws + off);     off += ((size_t)(N + 1) * sizeof(int) + 255) & ~(size_t)255;
    int* cursor = (int*)(ws + off);        off += ((size_t)N * sizeof(int) + 255) & ~(size_t)255;
    int* esrc = (int*)(ws + off);          off += ((size_t)E * sizeof(int) + 255) & ~(size_t)255;
    float* temb = (float*)(ws + off);      off += OUTC * sizeof(float);

    const int* srcIdx = ei;
    const int* dstIdx = ei + E;

    k_zero<<<(N + 255) / 256, 256, 0, stream>>>(counts, N);
    k_count<<<(E + 255) / 256, 256, 0, stream>>>(dstIdx, counts, E);
    k_dinv<<<(N + 255) / 256, 256, 0, stream>>>(counts, dinv, N);
    k_scan<<<1, SCAN_T, 0, stream>>>(counts, row_start, cursor, N);
    k_scatter<<<(E + 255) / 256, 256, 0, stream>>>(srcIdx, dstIdx, cursor, esrc, E);
    k_temb<<<OUTC, 256, 0, stream>>>(t_emb, Wt, bt, temb, TC);
    k_wt<<<dim3(INC / 32, OUTC / 32), 256, 0, stream>>>(W, WT);

    dim3 gemm_grid((N + 127) / 128, OUTC / 128);
    k_gemm_mfma<<<gemm_grid, 256, 0, stream>>>(x, WT, xwb, N);

    k_gather<<<N, 128, 0, stream>>>(esrc, row_start, xwb, dinv, b, temb, out, N);
}

// Round 4
// 174.525 us; speedup vs baseline: 7.3940x; 1.0548x over previous
//
#include <hip/hip_runtime.h>

#define OUTC 512
#define INC 512
#define SCAN_T 1024

typedef __bf16 bf16x8 __attribute__((ext_vector_type(8)));
typedef float f32x4 __attribute__((ext_vector_type(4)));

static __device__ __forceinline__ unsigned short f2bf(float f) {
    unsigned u = __float_as_uint(f);
    unsigned r = u + 0x7fffu + ((u >> 16) & 1u);  // RNE
    return (unsigned short)(r >> 16);
}

// ---------- CSR build ----------
__global__ void k_count(const int* __restrict__ dst, int* __restrict__ counts, int E) {
    int e = blockIdx.x * blockDim.x + threadIdx.x;
    if (e < E) atomicAdd(&counts[dst[e]], 1);
}

// scan + dinv fold
__global__ __launch_bounds__(SCAN_T) void k_scan(const int* __restrict__ counts,
                                                 int* __restrict__ row_start,
                                                 int* __restrict__ cursor,
                                                 float* __restrict__ dinv, int N) {
    __shared__ int sums[SCAN_T];
    int t = threadIdx.x;
    int C = (N + SCAN_T - 1) / SCAN_T;
    int lo = t * C;
    int hi = lo + C; if (hi > N) hi = N; if (lo > N) lo = N;
    int s = 0;
    for (int i = lo; i < hi; ++i) s += counts[i];
    sums[t] = s;
    __syncthreads();
    for (int off = 1; off < SCAN_T; off <<= 1) {
        int v = (t >= off) ? sums[t - off] : 0;
        __syncthreads();
        sums[t] += v;
        __syncthreads();
    }
    int run = (t == 0) ? 0 : sums[t - 1];
    for (int i = lo; i < hi; ++i) {
        int c = counts[i];
        row_start[i] = run;
        cursor[i] = run;
        dinv[i] = rsqrtf((float)c + 1.0f);
        run += c;
    }
    if (hi == N) row_start[N] = run;
}

__global__ void k_scatter(const int* __restrict__ src, const int* __restrict__ dst,
                          int* __restrict__ cursor, int* __restrict__ esrc, int E) {
    int e = blockIdx.x * blockDim.x + threadIdx.x;
    if (e < E) {
        int d = dst[e];
        int pos = atomicAdd(&cursor[d], 1);
        esrc[pos] = src[e];
    }
}

// ---------- time embedding + bias fold: temb[j] = t_emb@Wt + bt[j] + b[j] ----------
__global__ __launch_bounds__(256) void k_temb(const float* __restrict__ t_emb,
                                              const float* __restrict__ Wt,
                                              const float* __restrict__ bt,
                                              const float* __restrict__ b,
                                              float* __restrict__ temb, int TC) {
    __shared__ float red[256];
    int j = blockIdx.x;
    int t = threadIdx.x;
    float p = 0.0f;
    for (int k = t; k < TC; k += 256) p += t_emb[k] * Wt[(size_t)k * OUTC + j];
    red[t] = p;
    __syncthreads();
    for (int s = 128; s > 0; s >>= 1) {
        if (t < s) red[t] += red[t + s];
        __syncthreads();
    }
    if (t == 0) temb[j] = red[0] + bt[j] + b[j];
}

// ---------- X -> bf16 (padded with zero rows to Mpad) ----------
__global__ __launch_bounds__(256) void k_xb(const float* __restrict__ x,
                                            unsigned short* __restrict__ xb,
                                            int M, int Mpad) {
    int idx = blockIdx.x * 256 + threadIdx.x;  // one per 8 elements
    int total = Mpad * (INC / 8);
    if (idx >= total) return;
    int row = idx >> 6;
    int kg = (idx & 63) * 8;
    ushort4 h0 = make_ushort4(0, 0, 0, 0), h1 = make_ushort4(0, 0, 0, 0);
    if (row < M) {
        float4 v0 = *(const float4*)(x + (size_t)row * INC + kg);
        float4 v1 = *(const float4*)(x + (size_t)row * INC + kg + 4);
        h0 = make_ushort4(f2bf(v0.x), f2bf(v0.y), f2bf(v0.z), f2bf(v0.w));
        h1 = make_ushort4(f2bf(v1.x), f2bf(v1.y), f2bf(v1.z), f2bf(v1.w));
    }
    *(ushort4*)(xb + (size_t)row * INC + kg) = h0;
    *(ushort4*)(xb + (size_t)row * INC + kg + 4) = h1;
}

// ---------- W -> transposed bf16: wtb[n][k] ----------
__global__ __launch_bounds__(256) void k_wtb(const float* __restrict__ W,
                                             unsigned short* __restrict__ wtb) {
    __shared__ float tile[32][33];
    int bk = blockIdx.x * 32, bn = blockIdx.y * 32;
    int tx = threadIdx.x & 31, ty = threadIdx.x >> 5;  // ty 0..7
    for (int r = ty; r < 32; r += 8)
        tile[r][tx] = W[(size_t)(bk + r) * OUTC + bn + tx];
    __syncthreads();
    for (int r = ty; r < 32; r += 8)
        wtb[(size_t)(bn + r) * INC + bk + tx] = f2bf(tile[tx][r]);
}

// ---------- LDS-free 1-wave MFMA GEMM: xwb[Mpad,512](bf16) = xb @ wtb^T ----------
// 64x64 tile per 64-thread block, 4x4 16x16x32 fragments, direct global frag loads
__global__ __launch_bounds__(64) void k_gemm(const unsigned short* __restrict__ xb,
                                             const unsigned short* __restrict__ wtb,
                                             unsigned short* __restrict__ xwb) {
    const int m0 = blockIdx.x * 64;
    const int n0 = blockIdx.y * 64;
    const int lane = threadIdx.x;
    const int l15 = lane & 15;
    const int k8 = (lane >> 4) * 8;

    const unsigned short* Ab = xb + (size_t)(m0 + l15) * INC + k8;
    const unsigned short* Bb = wtb + (size_t)(n0 + l15) * INC + k8;

    f32x4 acc[4][4];
#pragma unroll
    for (int t = 0; t < 4; ++t)
#pragma unroll
        for (int u = 0; u < 4; ++u)
            acc[t][u] = (f32x4){0.f, 0.f, 0.f, 0.f};

#pragma unroll 2
    for (int k0 = 0; k0 < INC; k0 += 32) {
        bf16x8 af[4], bf[4];
#pragma unroll
        for (int t = 0; t < 4; ++t)
            af[t] = *(const bf16x8*)(Ab + (size_t)t * 16 * INC + k0);
#pragma unroll
        for (int u = 0; u < 4; ++u)
            bf[u] = *(const bf16x8*)(Bb + (size_t)u * 16 * INC + k0);
#pragma unroll
        for (int u = 0; u < 4; ++u)
#pragma unroll
            for (int t = 0; t < 4; ++t)
                acc[t][u] = __builtin_amdgcn_mfma_f32_16x16x32_bf16(af[t], bf[u], acc[t][u], 0, 0, 0);
    }

    const int rbase = (lane >> 4) * 4;
#pragma unroll
    for (int t = 0; t < 4; ++t)
#pragma unroll
        for (int u = 0; u < 4; ++u) {
            int gcol = n0 + u * 16 + l15;
#pragma unroll
            for (int r = 0; r < 4; ++r) {
                int grow = m0 + t * 16 + rbase + r;  // always < Mpad (padded)
                xwb[(size_t)grow * OUTC + gcol] = f2bf(acc[t][u][r]);
            }
        }
}

// ---------- CSR gather: one wave per node, 8 cols/lane ----------
static __device__ __forceinline__ void acc8(float* a, uint4 r, float nrm) {
    a[0] += nrm * __uint_as_float(r.x << 16);
    a[1] += nrm * __uint_as_float(r.x & 0xffff0000u);
    a[2] += nrm * __uint_as_float(r.y << 16);
    a[3] += nrm * __uint_as_float(r.y & 0xffff0000u);
    a[4] += nrm * __uint_as_float(r.z << 16);
    a[5] += nrm * __uint_as_float(r.z & 0xffff0000u);
    a[6] += nrm * __uint_as_float(r.w << 16);
    a[7] += nrm * __uint_as_float(r.w & 0xffff0000u);
}

__global__ __launch_bounds__(256) void k_gather(const int* __restrict__ esrc,
                                                const int* __restrict__ row_start,
                                                const unsigned short* __restrict__ XWB,
                                                const float* __restrict__ dinv,
                                                const float* __restrict__ temb,
                                                float* __restrict__ out, int N) {
    int node = blockIdx.x * 4 + (threadIdx.x >> 6);
    if (node >= N) return;
    int lane = threadIdx.x & 63;
    int c = lane * 8;
    int s0 = row_start[node];
    int s1 = row_start[node + 1];
    float di = dinv[node];

    float a[8];
    {
        uint4 r = *(const uint4*)(XWB + (size_t)node * OUTC + c);
        float4 t0 = *(const float4*)(temb + c);
        float4 t1 = *(const float4*)(temb + c + 4);
        float nd = di * di;
        a[0] = t0.x; a[1] = t0.y; a[2] = t0.z; a[3] = t0.w;
        a[4] = t1.x; a[5] = t1.y; a[6] = t1.z; a[7] = t1.w;
        acc8(a, r, nd);
    }

    int i = s0;
    for (; i + 2 <= s1; i += 2) {
        int sA = esrc[i];
        int sB = esrc[i + 1];
        float nA = dinv[sA] * di;
        float nB = dinv[sB] * di;
        uint4 rA = *(const uint4*)(XWB + (size_t)sA * OUTC + c);
        uint4 rB = *(const uint4*)(XWB + (size_t)sB * OUTC + c);
        acc8(a, rA, nA);
        acc8(a, rB, nB);
    }
    if (i < s1) {
        int sA = esrc[i];
        float nA = dinv[sA] * di;
        uint4 rA = *(const uint4*)(XWB + (size_t)sA * OUTC + c);
        acc8(a, rA, nA);
    }

    float* op = out + (size_t)node * OUTC + c;
    *(float4*)(op)     = make_float4(a[0], a[1], a[2], a[3]);
    *(float4*)(op + 4) = make_float4(a[4], a[5], a[6], a[7]);
}

extern "C" void kernel_launch(void* const* d_in, const int* in_sizes, int n_in,
                              void* d_out, int out_size, void* d_ws, size_t ws_size,
                              hipStream_t stream) {
    const float* x     = (const float*)d_in[0];
    const float* t_emb = (const float*)d_in[1];
    const int*   ei    = (const int*)d_in[2];
    const float* W     = (const float*)d_in[3];
    const float* b     = (const float*)d_in[4];
    const float* Wt    = (const float*)d_in[5];
    const float* bt    = (const float*)d_in[6];
    float* out = (float*)d_out;

    const int N  = in_sizes[0] / INC;   // 10000
    const int E  = in_sizes[2] / 2;     // 160000
    const int TC = in_sizes[1];         // 256
    const int Mpad = (N + 63) & ~63;    // 10048

    char* ws = (char*)d_ws;
    size_t off = 0;
    unsigned short* xb  = (unsigned short*)(ws + off); off += (size_t)Mpad * INC * 2;
    unsigned short* xwb = (unsigned short*)(ws + off); off += (size_t)Mpad * OUTC * 2;
    unsigned short* wtb = (unsigned short*)(ws + off); off += (size_t)INC * OUTC * 2;
    float* dinv = (float*)(ws + off);      off += ((size_t)N * 4 + 255) & ~(size_t)255;
    int* counts = (int*)(ws + off);        off += ((size_t)N * 4 + 255) & ~(size_t)255;
    int* row_start = (int*)(ws + off);     off += ((size_t)(N + 1) * 4 + 255) & ~(size_t)255;
    int* cursor = (int*)(ws + off);        off += ((size_t)N * 4 + 255) & ~(size_t)255;
    int* esrc = (int*)(ws + off);          off += ((size_t)E * 4 + 255) & ~(size_t)255;
    float* temb = (float*)(ws + off);      off += OUTC * 4;

    const int* srcIdx = ei;
    const int* dstIdx = ei + E;

    hipMemsetAsync(counts, 0, (size_t)N * sizeof(int), stream);
    k_count<<<(E + 255) / 256, 256, 0, stream>>>(dstIdx, counts, E);
    k_scan<<<1, SCAN_T, 0, stream>>>(counts, row_start, cursor, dinv, N);
    k_scatter<<<(E + 255) / 256, 256, 0, stream>>>(srcIdx, dstIdx, cursor, esrc, E);
    k_temb<<<OUTC, 256, 0, stream>>>(t_emb, Wt, bt, b, temb, TC);
    k_xb<<<(Mpad * (INC / 8) + 255) / 256, 256, 0, stream>>>(x, xb, N, Mpad);
    k_wtb<<<dim3(INC / 32, OUTC / 32), 256, 0, stream>>>(W, wtb);

    dim3 gemm_grid(Mpad / 64, OUTC / 64);
    k_gemm<<<gemm_grid, 64, 0, stream>>>(xb, wtb, xwb);

    k_gather<<<(N + 3) / 4, 256, 0, stream>>>(esrc, row_start, xwb, dinv, temb, out, N);
}